// Round 5
// baseline (963.513 us; speedup 1.0000x reference)
//
#include <hip/hip_runtime.h>

#define NN 100000
#define NE 1600000
#define DD 64
#define NBKT 800      // buckets of BSZ nodes; 800*125 == NN
#define BSZ 125
#define HTILE 6250    // hist: 256 blocks * 6250 == NE
#define PTILE 25000   // part: 64 blocks * 25000 == NE (long runs -> low write amp)

__device__ __forceinline__ float fsig(float x) {
    return __fdividef(1.0f, 1.0f + __expf(-x));
}
__device__ __forceinline__ float ftanh(float x) {
    return __fdividef(2.0f, 1.0f + __expf(-2.0f * x)) - 1.0f;
}
__device__ __forceinline__ unsigned int bf16rne(float a) {
    unsigned int u = __float_as_uint(a);
    return (u + 0x7fffu + ((u >> 16) & 1u)) >> 16;
}

// ---- Bucket histogram ---------------------------------------------------
__global__ __launch_bounds__(256) void hist_k(const int* __restrict__ dst,
                                              unsigned* __restrict__ bcnt) {
    __shared__ unsigned cnt[NBKT];
    const int tid = threadIdx.x;
    for (int i = tid; i < NBKT; i += 256) cnt[i] = 0u;
    __syncthreads();
    const int base = blockIdx.x * HTILE;
    for (int i = tid; i < HTILE; i += 256)
        atomicAdd(&cnt[(unsigned)dst[base + i] / BSZ], 1u);
    __syncthreads();
    for (int i = tid; i < NBKT; i += 256)
        if (cnt[i]) atomicAdd(&bcnt[i], cnt[i]);
}

// ---- Exclusive scan over 800 bucket counts ------------------------------
__global__ __launch_bounds__(1024) void scan_k(const unsigned* __restrict__ bcnt,
                                               unsigned* __restrict__ start,
                                               unsigned* __restrict__ gcur) {
    __shared__ unsigned s[1024];
    const int t = threadIdx.x;
    const unsigned v = (t < NBKT) ? bcnt[t] : 0u;
    s[t] = v;
    __syncthreads();
    for (int off = 1; off < 1024; off <<= 1) {
        const unsigned tmp = (t >= off) ? s[t - off] : 0u;
        __syncthreads();
        s[t] += tmp;
        __syncthreads();
    }
    if (t < NBKT) { start[t] = s[t] - v; gcur[t] = s[t] - v; }
    if (t == NBKT - 1) start[NBKT] = s[t];   // == NE
}

// ---- Partition edges into buckets ---------------------------------------
// 64 fat blocks: per block-bucket run ~31 edges = 250B contiguous -> write
// amp ~1.3x (vs 8x with 8B random scatter in R3/R4).
__global__ __launch_bounds__(512) void part_k(const int* __restrict__ src,
                                              const int* __restrict__ dst,
                                              const float* __restrict__ ew,
                                              unsigned* __restrict__ gcur,
                                              uint2* __restrict__ pairs) {
    __shared__ unsigned cnt[NBKT];
    __shared__ unsigned basep[NBKT];
    __shared__ unsigned off[NBKT];
    const int tid = threadIdx.x;
    for (int i = tid; i < NBKT; i += 512) { cnt[i] = 0u; off[i] = 0u; }
    __syncthreads();
    const int base = blockIdx.x * PTILE;
    for (int i = tid; i < PTILE; i += 512)
        atomicAdd(&cnt[(unsigned)dst[base + i] / BSZ], 1u);
    __syncthreads();
    for (int i = tid; i < NBKT; i += 512)
        basep[i] = cnt[i] ? atomicAdd(&gcur[i], cnt[i]) : 0u;
    __syncthreads();
    for (int i = tid; i < PTILE; i += 512) {
        const int e = base + i;
        const unsigned d = (unsigned)dst[e];
        const unsigned b = d / BSZ;
        const unsigned p = basep[b] + atomicAdd(&off[b], 1u);
        // pack: src (17 bits) | local-dst (7 bits) << 17
        pairs[p] = make_uint2((unsigned)src[e] | ((d - b * BSZ) << 17),
                              __float_as_uint(ew[e]));
    }
}

// ---- Bucket accumulate: LDS f32 atomics ---------------------------------
// One 512-thread block per bucket (32,000B LDS). Key fix vs R4: per-edge
// broadcast uses v_readlane (uniform index asserted via builtin) instead of
// ds_bpermute, so the gather loads pipeline (SGPR saddr form, unroll 8 ->
// >=8 rows in flight per wave; ~25 waves/CU).
__global__ __launch_bounds__(512) void accum_k(const float* __restrict__ h,
                                               const uint2* __restrict__ pairs,
                                               const unsigned* __restrict__ start,
                                               float* __restrict__ hnew) {
    __shared__ float sacc[BSZ * DD];
    const int tid = threadIdx.x;
    const int lane = tid & 63;
    const int wave = tid >> 6;
    for (int i = tid; i < BSZ * DD; i += 512) sacc[i] = 0.0f;
    __syncthreads();
    const unsigned s0 = start[blockIdx.x];
    const unsigned s1 = start[blockIdx.x + 1];
    for (unsigned cbase = s0 + (unsigned)(wave << 6); cbase < s1; cbase += 512u) {
        const int m = (int)min(64u, s1 - cbase);
        uint2 pr = make_uint2(0u, 0u);
        if (lane < m) pr = pairs[cbase + lane];      // coalesced 8B/lane
        #pragma unroll 8
        for (int j = 0; j < m; ++j) {                // m is wave-uniform
            const int sj = __builtin_amdgcn_readlane((int)pr.x, j);
            const int wj = __builtin_amdgcn_readlane((int)pr.y, j);
            const float v = h[(unsigned)(sj & 0x1FFFF) * DD + lane];
            atomicAdd(&sacc[(unsigned)(sj >> 17) * DD + lane],
                      __int_as_float(wj) * v);
        }
    }
    __syncthreads();
    const unsigned nb = (unsigned)blockIdx.x * (BSZ * DD);
    for (int i = tid; i < BSZ * DD; i += 512)
        hnew[nb + i] = sacc[i];                      // coalesced, once per node
}

// ---- GRU cell -----------------------------------------------------------
// Weights bf16-packed as uint4 over k8-groups -> ds_read_b128 (16B/lane,
// conflict-free), 4x fewer LDS ops per k-step than the b32 version.
// LDS: 2*24,576 + 4,096 = 53,248B -> 3 blocks/CU.
__global__ __launch_bounds__(256, 3) void gru_k(
    const float* hnew, const float* __restrict__ h,
    const float* __restrict__ Wih, const float* __restrict__ Whh,
    const float* __restrict__ bih, const float* __restrict__ bhh,
    float* out)
{
    __shared__ uint4 W4I[8][192];      // [k8][row]: 8 bf16 along k
    __shared__ uint4 W4H[8][192];
    __shared__ unsigned xh[16][64];    // [node][k]: (bf16(x)<<16)|bf16(h)

    const int tid = threadIdx.x;
    for (int f = tid; f < 192 * 8; f += 256) {
        const int row = f >> 3, k8 = f & 7;
        const float4 a0 = *(const float4*)(Wih + row * 64 + k8 * 8);
        const float4 a1 = *(const float4*)(Wih + row * 64 + k8 * 8 + 4);
        const float4 b0 = *(const float4*)(Whh + row * 64 + k8 * 8);
        const float4 b1 = *(const float4*)(Whh + row * 64 + k8 * 8 + 4);
        W4I[k8][row] = make_uint4(bf16rne(a0.x) | (bf16rne(a0.y) << 16),
                                  bf16rne(a0.z) | (bf16rne(a0.w) << 16),
                                  bf16rne(a1.x) | (bf16rne(a1.y) << 16),
                                  bf16rne(a1.z) | (bf16rne(a1.w) << 16));
        W4H[k8][row] = make_uint4(bf16rne(b0.x) | (bf16rne(b0.y) << 16),
                                  bf16rne(b0.z) | (bf16rne(b0.w) << 16),
                                  bf16rne(b1.x) | (bf16rne(b1.y) << 16),
                                  bf16rne(b1.z) | (bf16rne(b1.w) << 16));
    }
    __syncthreads();

    const int lane = tid & 63;
    const int w4 = (tid >> 6) << 2;

    const float b_ir = bih[lane], b_iz = bih[64 + lane], b_in = bih[128 + lane];
    const float b_hr = bhh[lane], b_hz = bhh[64 + lane], b_hn = bhh[128 + lane];

    for (int g = blockIdx.x; g < NN / 16; g += gridDim.x) {
        const int nb = g * 16 + w4;
        float hreg[4];
        #pragma unroll
        for (int i = 0; i < 4; ++i) {
            const float xv = hnew[(nb + i) * DD + lane];
            hreg[i] = h[(nb + i) * DD + lane];
            xh[w4 + i][lane] = (bf16rne(xv) << 16) | bf16rne(hreg[i]);  // wave-private
        }
        float air[4], aiz[4], ain[4], ahr[4], ahz[4], ahn[4];
        #pragma unroll
        for (int i = 0; i < 4; ++i) {
            air[i] = b_ir; aiz[i] = b_iz; ain[i] = b_in;
            ahr[i] = b_hr; ahz[i] = b_hz; ahn[i] = b_hn;
        }
        #pragma unroll
        for (int k8 = 0; k8 < 8; ++k8) {
            const uint4 uir = W4I[k8][lane];
            const uint4 uiz = W4I[k8][64 + lane];
            const uint4 uin = W4I[k8][128 + lane];
            const uint4 uhr = W4H[k8][lane];
            const uint4 uhz = W4H[k8][64 + lane];
            const uint4 uhn = W4H[k8][128 + lane];
            const unsigned wi_r[4] = {uir.x, uir.y, uir.z, uir.w};
            const unsigned wi_z[4] = {uiz.x, uiz.y, uiz.z, uiz.w};
            const unsigned wi_n[4] = {uin.x, uin.y, uin.z, uin.w};
            const unsigned wh_r[4] = {uhr.x, uhr.y, uhr.z, uhr.w};
            const unsigned wh_z[4] = {uhz.x, uhz.y, uhz.z, uhz.w};
            const unsigned wh_n[4] = {uhn.x, uhn.y, uhn.z, uhn.w};
            #pragma unroll
            for (int i = 0; i < 4; ++i) {
                const uint4 ua = *(const uint4*)(&xh[w4 + i][k8 * 8]);      // k..k+3
                const uint4 ub = *(const uint4*)(&xh[w4 + i][k8 * 8 + 4]);  // k+4..k+7
                const unsigned xw[8] = {ua.x, ua.y, ua.z, ua.w, ub.x, ub.y, ub.z, ub.w};
                #pragma unroll
                for (int t = 0; t < 8; ++t) {
                    const float xv = __uint_as_float(xw[t] & 0xffff0000u);
                    const float hv = __uint_as_float(xw[t] << 16);
                    const unsigned sel = (t & 1) ? 0xffff0000u : 0u;  // low/high bf16
                    const float wr = (t & 1) ? __uint_as_float(wi_r[t >> 1] & 0xffff0000u)
                                             : __uint_as_float(wi_r[t >> 1] << 16);
                    const float wz = (t & 1) ? __uint_as_float(wi_z[t >> 1] & 0xffff0000u)
                                             : __uint_as_float(wi_z[t >> 1] << 16);
                    const float wn = (t & 1) ? __uint_as_float(wi_n[t >> 1] & 0xffff0000u)
                                             : __uint_as_float(wi_n[t >> 1] << 16);
                    const float vr = (t & 1) ? __uint_as_float(wh_r[t >> 1] & 0xffff0000u)
                                             : __uint_as_float(wh_r[t >> 1] << 16);
                    const float vz = (t & 1) ? __uint_as_float(wh_z[t >> 1] & 0xffff0000u)
                                             : __uint_as_float(wh_z[t >> 1] << 16);
                    const float vn = (t & 1) ? __uint_as_float(wh_n[t >> 1] & 0xffff0000u)
                                             : __uint_as_float(wh_n[t >> 1] << 16);
                    (void)sel;
                    air[i] = fmaf(xv, wr, air[i]);
                    aiz[i] = fmaf(xv, wz, aiz[i]);
                    ain[i] = fmaf(xv, wn, ain[i]);
                    ahr[i] = fmaf(hv, vr, ahr[i]);
                    ahz[i] = fmaf(hv, vz, ahz[i]);
                    ahn[i] = fmaf(hv, vn, ahn[i]);
                }
            }
        }
        #pragma unroll
        for (int i = 0; i < 4; ++i) {
            const float r  = fsig(air[i] + ahr[i]);
            const float z  = fsig(aiz[i] + ahz[i]);
            const float nv = ftanh(fmaf(r, ahn[i], ain[i]));
            out[(nb + i) * DD + lane] = fmaf(z, hreg[i] - nv, nv);
        }
    }
}

extern "C" void kernel_launch(void* const* d_in, const int* in_sizes, int n_in,
                              void* d_out, int out_size, void* d_ws, size_t ws_size,
                              hipStream_t stream)
{
    const float* h   = (const float*)d_in[0];
    const float* ew  = (const float*)d_in[1];
    const float* Wih = (const float*)d_in[2];
    const float* Whh = (const float*)d_in[3];
    const float* bih = (const float*)d_in[4];
    const float* bhh = (const float*)d_in[5];
    const int*   src = (const int*)d_in[6];
    const int*   dst = (const int*)d_in[7];
    float* out = (float*)d_out;

    // ws layout (~12.82 MB)
    char* ws = (char*)d_ws;
    unsigned* bcnt  = (unsigned*)(ws);            // 3,200 B
    unsigned* start = (unsigned*)(ws + 3200);     // 3,204 B
    unsigned* gcur  = (unsigned*)(ws + 6408);     // 3,200 B
    uint2*    pairs = (uint2*)   (ws + 16384);    // 12.8 MB

    hipMemsetAsync(bcnt, 0, NBKT * sizeof(unsigned), stream);
    hist_k <<<256, 256, 0, stream>>>(dst, bcnt);
    scan_k <<<1, 1024, 0, stream>>>(bcnt, start, gcur);
    part_k <<<64, 512, 0, stream>>>(src, dst, ew, gcur, pairs);
    accum_k<<<NBKT, 512, 0, stream>>>(h, pairs, start, out);  // out = hnew scratch
    gru_k  <<<768, 256, 0, stream>>>(out, h, Wih, Whh, bih, bhh, out);
}

// Round 6
// 952.908 us; speedup vs baseline: 1.0111x; 1.0111x over previous
//
#include <hip/hip_runtime.h>

#define NN 100000
#define NE 1600000
#define DD 64
#define NBKT 800      // buckets of BSZ nodes; 800*125 == NN
#define BSZ 125
#define HTILE 6250    // hist: 256 blocks * 6250 == NE
#define PTILE 25000   // part: 64 blocks * 25000 == NE (long runs -> low write amp)

__device__ __forceinline__ float fsig(float x) {
    return __fdividef(1.0f, 1.0f + __expf(-x));
}
__device__ __forceinline__ float ftanh(float x) {
    return __fdividef(2.0f, 1.0f + __expf(-2.0f * x)) - 1.0f;
}
__device__ __forceinline__ unsigned int bf16rne(float a) {
    unsigned int u = __float_as_uint(a);
    return (u + 0x7fffu + ((u >> 16) & 1u)) >> 16;
}

// ---- Bucket histogram ---------------------------------------------------
__global__ __launch_bounds__(256) void hist_k(const int* __restrict__ dst,
                                              unsigned* __restrict__ bcnt) {
    __shared__ unsigned cnt[NBKT];
    const int tid = threadIdx.x;
    for (int i = tid; i < NBKT; i += 256) cnt[i] = 0u;
    __syncthreads();
    const int base = blockIdx.x * HTILE;
    for (int i = tid; i < HTILE; i += 256)
        atomicAdd(&cnt[(unsigned)dst[base + i] / BSZ], 1u);
    __syncthreads();
    for (int i = tid; i < NBKT; i += 256)
        if (cnt[i]) atomicAdd(&bcnt[i], cnt[i]);
}

// ---- Exclusive scan over 800 bucket counts ------------------------------
__global__ __launch_bounds__(1024) void scan_k(const unsigned* __restrict__ bcnt,
                                               unsigned* __restrict__ start,
                                               unsigned* __restrict__ gcur) {
    __shared__ unsigned s[1024];
    const int t = threadIdx.x;
    const unsigned v = (t < NBKT) ? bcnt[t] : 0u;
    s[t] = v;
    __syncthreads();
    for (int off = 1; off < 1024; off <<= 1) {
        const unsigned tmp = (t >= off) ? s[t - off] : 0u;
        __syncthreads();
        s[t] += tmp;
        __syncthreads();
    }
    if (t < NBKT) { start[t] = s[t] - v; gcur[t] = s[t] - v; }
    if (t == NBKT - 1) start[NBKT] = s[t];   // == NE
}

// ---- Partition edges into buckets ---------------------------------------
__global__ __launch_bounds__(512) void part_k(const int* __restrict__ src,
                                              const int* __restrict__ dst,
                                              const float* __restrict__ ew,
                                              unsigned* __restrict__ gcur,
                                              uint2* __restrict__ pairs) {
    __shared__ unsigned cnt[NBKT];
    __shared__ unsigned basep[NBKT];
    __shared__ unsigned off[NBKT];
    const int tid = threadIdx.x;
    for (int i = tid; i < NBKT; i += 512) { cnt[i] = 0u; off[i] = 0u; }
    __syncthreads();
    const int base = blockIdx.x * PTILE;
    for (int i = tid; i < PTILE; i += 512)
        atomicAdd(&cnt[(unsigned)dst[base + i] / BSZ], 1u);
    __syncthreads();
    for (int i = tid; i < NBKT; i += 512)
        basep[i] = cnt[i] ? atomicAdd(&gcur[i], cnt[i]) : 0u;
    __syncthreads();
    for (int i = tid; i < PTILE; i += 512) {
        const int e = base + i;
        const unsigned d = (unsigned)dst[e];
        const unsigned b = d / BSZ;
        const unsigned p = basep[b] + atomicAdd(&off[b], 1u);
        // pack: src (17 bits) | local-dst (7 bits) << 17
        pairs[p] = make_uint2((unsigned)src[e] | ((d - b * BSZ) << 17),
                              __float_as_uint(ew[e]));
    }
}

// ---- Bucket accumulate: LDS f32 atomics ---------------------------------
// Key fix vs R5: compile-time batches of 8 -> phase 1 issues 8 independent
// gathers (no consumer in between => compiler emits 8 global_loads then
// progressive vmcnt), phase 2 does the 8 LDS atomics. MLP 1 -> 8 per wave.
// Edge idx/weight stay in SGPRs via readlane (uniform), payload = 8 VGPRs.
__global__ __launch_bounds__(512) void accum_k(const float* __restrict__ h,
                                               const uint2* __restrict__ pairs,
                                               const unsigned* __restrict__ start,
                                               float* __restrict__ hnew) {
    __shared__ float sacc[BSZ * DD];
    const int tid = threadIdx.x;
    const int lane = tid & 63;
    const int wave = tid >> 6;
    for (int i = tid; i < BSZ * DD; i += 512) sacc[i] = 0.0f;
    __syncthreads();
    const unsigned s0 = start[blockIdx.x];
    const unsigned s1 = start[blockIdx.x + 1];
    for (unsigned cbase = s0 + (unsigned)(wave << 6); cbase < s1; cbase += 512u) {
        const int m = (int)min(64u, s1 - cbase);
        uint2 pr = make_uint2(0u, 0u);
        if (lane < m) pr = pairs[cbase + lane];      // coalesced 8B/lane
        if (m == 64) {
            #pragma unroll
            for (int t = 0; t < 64; t += 8) {
                unsigned ss[8]; float ww[8], vv[8];
                #pragma unroll
                for (int u = 0; u < 8; ++u) {        // phase 1: 8 loads in flight
                    ss[u] = (unsigned)__builtin_amdgcn_readlane((int)pr.x, t + u);
                    ww[u] = __int_as_float(__builtin_amdgcn_readlane((int)pr.y, t + u));
                    vv[u] = h[(ss[u] & 0x1FFFFu) * DD + lane];
                }
                #pragma unroll
                for (int u = 0; u < 8; ++u)          // phase 2: 8 LDS atomics
                    atomicAdd(&sacc[(ss[u] >> 17) * DD + lane], ww[u] * vv[u]);
            }
        } else {
            for (int j = 0; j < m; ++j) {
                const unsigned sj = (unsigned)__builtin_amdgcn_readlane((int)pr.x, j);
                const float    wj = __int_as_float(__builtin_amdgcn_readlane((int)pr.y, j));
                atomicAdd(&sacc[(sj >> 17) * DD + lane],
                          wj * h[(sj & 0x1FFFFu) * DD + lane]);
            }
        }
    }
    __syncthreads();
    const unsigned nb = (unsigned)blockIdx.x * (BSZ * DD);
    for (int i = tid; i < BSZ * DD; i += 512)
        hnew[nb + i] = sacc[i];                      // coalesced, once per node
}

// ---- GRU cell (unchanged from R5 for clean attribution) -----------------
__global__ __launch_bounds__(256, 3) void gru_k(
    const float* hnew, const float* __restrict__ h,
    const float* __restrict__ Wih, const float* __restrict__ Whh,
    const float* __restrict__ bih, const float* __restrict__ bhh,
    float* out)
{
    __shared__ uint4 W4I[8][192];      // [k8][row]: 8 bf16 along k
    __shared__ uint4 W4H[8][192];
    __shared__ unsigned xh[16][64];    // [node][k]: (bf16(x)<<16)|bf16(h)

    const int tid = threadIdx.x;
    for (int f = tid; f < 192 * 8; f += 256) {
        const int row = f >> 3, k8 = f & 7;
        const float4 a0 = *(const float4*)(Wih + row * 64 + k8 * 8);
        const float4 a1 = *(const float4*)(Wih + row * 64 + k8 * 8 + 4);
        const float4 b0 = *(const float4*)(Whh + row * 64 + k8 * 8);
        const float4 b1 = *(const float4*)(Whh + row * 64 + k8 * 8 + 4);
        W4I[k8][row] = make_uint4(bf16rne(a0.x) | (bf16rne(a0.y) << 16),
                                  bf16rne(a0.z) | (bf16rne(a0.w) << 16),
                                  bf16rne(a1.x) | (bf16rne(a1.y) << 16),
                                  bf16rne(a1.z) | (bf16rne(a1.w) << 16));
        W4H[k8][row] = make_uint4(bf16rne(b0.x) | (bf16rne(b0.y) << 16),
                                  bf16rne(b0.z) | (bf16rne(b0.w) << 16),
                                  bf16rne(b1.x) | (bf16rne(b1.y) << 16),
                                  bf16rne(b1.z) | (bf16rne(b1.w) << 16));
    }
    __syncthreads();

    const int lane = tid & 63;
    const int w4 = (tid >> 6) << 2;

    const float b_ir = bih[lane], b_iz = bih[64 + lane], b_in = bih[128 + lane];
    const float b_hr = bhh[lane], b_hz = bhh[64 + lane], b_hn = bhh[128 + lane];

    for (int g = blockIdx.x; g < NN / 16; g += gridDim.x) {
        const int nb = g * 16 + w4;
        float hreg[4];
        #pragma unroll
        for (int i = 0; i < 4; ++i) {
            const float xv = hnew[(nb + i) * DD + lane];
            hreg[i] = h[(nb + i) * DD + lane];
            xh[w4 + i][lane] = (bf16rne(xv) << 16) | bf16rne(hreg[i]);
        }
        float air[4], aiz[4], ain[4], ahr[4], ahz[4], ahn[4];
        #pragma unroll
        for (int i = 0; i < 4; ++i) {
            air[i] = b_ir; aiz[i] = b_iz; ain[i] = b_in;
            ahr[i] = b_hr; ahz[i] = b_hz; ahn[i] = b_hn;
        }
        #pragma unroll
        for (int k8 = 0; k8 < 8; ++k8) {
            const uint4 uir = W4I[k8][lane];
            const uint4 uiz = W4I[k8][64 + lane];
            const uint4 uin = W4I[k8][128 + lane];
            const uint4 uhr = W4H[k8][lane];
            const uint4 uhz = W4H[k8][64 + lane];
            const uint4 uhn = W4H[k8][128 + lane];
            const unsigned wi_r[4] = {uir.x, uir.y, uir.z, uir.w};
            const unsigned wi_z[4] = {uiz.x, uiz.y, uiz.z, uiz.w};
            const unsigned wi_n[4] = {uin.x, uin.y, uin.z, uin.w};
            const unsigned wh_r[4] = {uhr.x, uhr.y, uhr.z, uhr.w};
            const unsigned wh_z[4] = {uhz.x, uhz.y, uhz.z, uhz.w};
            const unsigned wh_n[4] = {uhn.x, uhn.y, uhn.z, uhn.w};
            #pragma unroll
            for (int i = 0; i < 4; ++i) {
                const uint4 ua = *(const uint4*)(&xh[w4 + i][k8 * 8]);
                const uint4 ub = *(const uint4*)(&xh[w4 + i][k8 * 8 + 4]);
                const unsigned xw[8] = {ua.x, ua.y, ua.z, ua.w, ub.x, ub.y, ub.z, ub.w};
                #pragma unroll
                for (int t = 0; t < 8; ++t) {
                    const float xv = __uint_as_float(xw[t] & 0xffff0000u);
                    const float hv = __uint_as_float(xw[t] << 16);
                    const float wr = (t & 1) ? __uint_as_float(wi_r[t >> 1] & 0xffff0000u)
                                             : __uint_as_float(wi_r[t >> 1] << 16);
                    const float wz = (t & 1) ? __uint_as_float(wi_z[t >> 1] & 0xffff0000u)
                                             : __uint_as_float(wi_z[t >> 1] << 16);
                    const float wn = (t & 1) ? __uint_as_float(wi_n[t >> 1] & 0xffff0000u)
                                             : __uint_as_float(wi_n[t >> 1] << 16);
                    const float vr = (t & 1) ? __uint_as_float(wh_r[t >> 1] & 0xffff0000u)
                                             : __uint_as_float(wh_r[t >> 1] << 16);
                    const float vz = (t & 1) ? __uint_as_float(wh_z[t >> 1] & 0xffff0000u)
                                             : __uint_as_float(wh_z[t >> 1] << 16);
                    const float vn = (t & 1) ? __uint_as_float(wh_n[t >> 1] & 0xffff0000u)
                                             : __uint_as_float(wh_n[t >> 1] << 16);
                    air[i] = fmaf(xv, wr, air[i]);
                    aiz[i] = fmaf(xv, wz, aiz[i]);
                    ain[i] = fmaf(xv, wn, ain[i]);
                    ahr[i] = fmaf(hv, vr, ahr[i]);
                    ahz[i] = fmaf(hv, vz, ahz[i]);
                    ahn[i] = fmaf(hv, vn, ahn[i]);
                }
            }
        }
        #pragma unroll
        for (int i = 0; i < 4; ++i) {
            const float r  = fsig(air[i] + ahr[i]);
            const float z  = fsig(aiz[i] + ahz[i]);
            const float nv = ftanh(fmaf(r, ahn[i], ain[i]));
            out[(nb + i) * DD + lane] = fmaf(z, hreg[i] - nv, nv);
        }
    }
}

extern "C" void kernel_launch(void* const* d_in, const int* in_sizes, int n_in,
                              void* d_out, int out_size, void* d_ws, size_t ws_size,
                              hipStream_t stream)
{
    const float* h   = (const float*)d_in[0];
    const float* ew  = (const float*)d_in[1];
    const float* Wih = (const float*)d_in[2];
    const float* Whh = (const float*)d_in[3];
    const float* bih = (const float*)d_in[4];
    const float* bhh = (const float*)d_in[5];
    const int*   src = (const int*)d_in[6];
    const int*   dst = (const int*)d_in[7];
    float* out = (float*)d_out;

    // ws layout (~12.82 MB)
    char* ws = (char*)d_ws;
    unsigned* bcnt  = (unsigned*)(ws);            // 3,200 B
    unsigned* start = (unsigned*)(ws + 3200);     // 3,204 B
    unsigned* gcur  = (unsigned*)(ws + 6408);     // 3,200 B
    uint2*    pairs = (uint2*)   (ws + 16384);    // 12.8 MB

    hipMemsetAsync(bcnt, 0, NBKT * sizeof(unsigned), stream);
    hist_k <<<256, 256, 0, stream>>>(dst, bcnt);
    scan_k <<<1, 1024, 0, stream>>>(bcnt, start, gcur);
    part_k <<<64, 512, 0, stream>>>(src, dst, ew, gcur, pairs);
    accum_k<<<NBKT, 512, 0, stream>>>(h, pairs, start, out);  // out = hnew scratch
    gru_k  <<<768, 256, 0, stream>>>(out, h, Wih, Whh, bih, bhh, out);
}